// Round 3
// baseline (323.322 us; speedup 1.0000x reference)
//
#include <hip/hip_runtime.h>

#define EPSC    1e-5f
#define LNEPS   1e-5f

typedef __attribute__((ext_vector_type(8))) short  short8;   // 8 bf16
typedef __attribute__((ext_vector_type(4))) float  floatx4;  // 4 fp32 acc

static __device__ __forceinline__ unsigned short f2bf(float f){
  union { float f; unsigned int u; } v; v.f = f;
  unsigned int u = v.u;
  u += 0x7FFFu + ((u >> 16) & 1u);   // round-to-nearest-even
  return (unsigned short)(u >> 16);
}
static __device__ __forceinline__ float bf2f(unsigned short h){
  union { unsigned int u; float f; } v; v.u = ((unsigned int)h) << 16;
  return v.f;
}

// ---------------------------------------------------------------------------
// K1: per-(n,c) sum/sumsq partials + per-group gram partials (bf16 MFMA).
// grid (quarter=4, g=4, n=32) = 512 blocks (2/CU), 256 threads.
// Each block: 64 ch x 1024 hw.
// ---------------------------------------------------------------------------
__global__ __launch_bounds__(256) void k_stats_gram(
    const float* __restrict__ X, float* __restrict__ S1p,
    float* __restrict__ S2p, float* __restrict__ gramP)
{
  const int q4 = blockIdx.x, g = blockIdx.y, n = blockIdx.z;
  const int t  = threadIdx.x;
  const int ch = t >> 2, f4 = t & 3;
  __shared__ unsigned short lt[64][88];   // bf16 tile, stride 88

  const float* rowb = X + (size_t)(n*256 + g*64 + ch)*4096 + q4*1024;

  float4 buf[4];
  #pragma unroll
  for (int i = 0; i < 4; ++i)
    buf[i] = *(const float4*)(rowb + (4*i + f4)*4);

  float s1 = 0.f, s2 = 0.f;
  floatx4 acc[4];
  #pragma unroll
  for (int i = 0; i < 4; ++i) acc[i] = (floatx4){0.f, 0.f, 0.f, 0.f};

  const int wv = t >> 6;
  const int l15 = t & 15, q = (t & 63) >> 4;

  for (int tile = 0; tile < 16; ++tile){
    #pragma unroll
    for (int i = 0; i < 4; ++i){
      float4 v = buf[i];
      s1 += (v.x + v.y) + (v.z + v.w);
      s2 += v.x*v.x + v.y*v.y + v.z*v.z + v.w*v.w;
      ushort4 b;
      b.x = f2bf(v.x); b.y = f2bf(v.y); b.z = f2bf(v.z); b.w = f2bf(v.w);
      *(ushort4*)&lt[ch][(4*i + f4)*4] = b;
    }
    __syncthreads();
    if (tile < 15){
      const float* nb = rowb + (tile + 1)*64;
      #pragma unroll
      for (int i = 0; i < 4; ++i)
        buf[i] = *(const float4*)(nb + (4*i + f4)*4);
    }
    #pragma unroll
    for (int k0 = 0; k0 < 64; k0 += 32){
      short8 af = *(const short8*)&lt[16*wv + l15][k0 + q*8];
      #pragma unroll
      for (int t4 = 0; t4 < 4; ++t4){
        short8 bf = *(const short8*)&lt[16*t4 + l15][k0 + q*8];
        acc[t4] = __builtin_amdgcn_mfma_f32_16x16x32_bf16(af, bf, acc[t4], 0, 0, 0);
      }
    }
    __syncthreads();
  }

  s1 += __shfl_down(s1, 2); s1 += __shfl_down(s1, 1);
  s2 += __shfl_down(s2, 2); s2 += __shfl_down(s2, 1);
  const int blk = n*16 + g*4 + q4;
  if (f4 == 0){ S1p[blk*64 + ch] = s1; S2p[blk*64 + ch] = s2; }

  float* gp = gramP + (size_t)blk*4096;
  #pragma unroll
  for (int t4 = 0; t4 < 4; ++t4)
    #pragma unroll
    for (int r = 0; r < 4; ++r)
      gp[(16*wv + 4*q + r)*64 + 16*t4 + l15] = acc[t4][r];
}

// ---------------------------------------------------------------------------
// K2: parallel reductions. blocks 0..63: gram -> SigmaS (raw). block 64:
// x_var (8192), total var sum, cmean (256).
// ---------------------------------------------------------------------------
__global__ __launch_bounds__(256) void k_reduce(
    const float* __restrict__ gramP, const float* __restrict__ S1p,
    const float* __restrict__ S2p,
    float* __restrict__ SigmaS, float* __restrict__ xvar,
    float* __restrict__ cmean, float* __restrict__ vsum)
{
  const int t = threadIdx.x, b = blockIdx.x;
  if (b < 64){
    const int idx = b*256 + t;              // [0, 16384)
    const int g = idx >> 12, e = idx & 4095;
    const float* p = gramP + (size_t)(g*4)*4096 + e;
    float s = 0.f;
    for (int n = 0; n < 32; ++n){
      s += (p[0] + p[4096]) + (p[2*4096] + p[3*4096]);
      p += 16*4096;
    }
    SigmaS[idx] = s;
  } else {
    __shared__ float red[256];
    float lsum = 0.f;
    #pragma unroll
    for (int i = 0; i < 32; ++i){
      const int idx = t + i*256;            // [0, 8192)
      const int n = idx >> 8, c = idx & 255;
      const int base = (n*16 + (c >> 6)*4)*64 + (c & 63);
      const float s1 = (S1p[base] + S1p[base+64]) + (S1p[base+128] + S1p[base+192]);
      const float s2 = (S2p[base] + S2p[base+64]) + (S2p[base+128] + S2p[base+192]);
      const float v = (s2 - s1*s1*(1.f/4096.f)) * (1.f/4095.f);
      xvar[idx] = v; lsum += v;
    }
    red[t] = lsum;
    __syncthreads();
    for (int s = 128; s > 0; s >>= 1){
      if (t < s) red[t] += red[t + s];
      __syncthreads();
    }
    if (t == 0) vsum[0] = red[0];
    {
      const int g = t >> 6, cc = t & 63;
      float s = 0.f;
      for (int n = 0; n < 32; ++n){
        const float* p = S1p + (n*16 + g*4)*64 + cc;
        s += (p[0] + p[64]) + (p[128] + p[192]);
      }
      cmean[t] = s * (1.f/131072.f);
    }
  }
}

// ---------------------------------------------------------------------------
// K3: blocks 0..3 = Newton-Schulz (MFMA, split-bf16); blocks 4..35 = SE (per-n)
// 256 threads. Writes PwT (transposed: PwT[g][e][d] = w*P[d][e]).
// ---------------------------------------------------------------------------
#define STR 72   // bf16 row stride (ushorts)

__global__ __launch_bounds__(256) void k_mid2(
    const float* __restrict__ SigmaS, const float* __restrict__ cmean,
    const float* __restrict__ xvar, const float* __restrict__ vsum,
    const float* __restrict__ fc1_w, const float* __restrict__ ln_g,
    const float* __restrict__ ln_b, const float* __restrict__ fc2_w,
    const float* __restrict__ xw,
    float* __restrict__ PwT, float* __restrict__ aOut)
{
  __shared__ __align__(16) unsigned short us[6*64*STR];   // SNh SNl Ph Pl Th Tl
  __shared__ float fbuf[512];
  const int t = threadIdx.x;
  const float wsig = 1.f / (1.f + __expf(-xw[0]));

  if (blockIdx.x < 4){
    // ---------------- Newton-Schulz ----------------
    const int g = blockIdx.x;
    const int w4 = t >> 6, l15 = t & 15, q = (t & 63) >> 4;
    unsigned short* SNh = us;
    unsigned short* SNl = us + 1*64*STR;
    unsigned short* Ph  = us + 2*64*STR;
    unsigned short* Pl_ = us + 3*64*STR;
    unsigned short* Th  = us + 4*64*STR;
    unsigned short* Tl  = us + 5*64*STR;
    float* cml = fbuf;          // 64
    float* rtr = fbuf + 64;

    if (t < 64) cml[t] = cmean[g*64 + t];
    __syncthreads();
    if (t < 64){
      const float cm = cml[t];
      float v = EPSC * (SigmaS[g*4096 + t*65] - 131072.f*cm*cm) + (1.f/131072.f);
      v += __shfl_xor(v, 32); v += __shfl_xor(v, 16);
      v += __shfl_xor(v, 8);  v += __shfl_xor(v, 4);
      v += __shfl_xor(v, 2);  v += __shfl_xor(v, 1);
      if (t == 0) rtr[0] = 1.f / v;
    }
    __syncthreads();
    const float rT = rtr[0];

    floatx4 Pf[4];
    #pragma unroll
    for (int nt = 0; nt < 4; ++nt){
      #pragma unroll
      for (int r = 0; r < 4; ++r){
        const int d = w4*16 + q*4 + r;
        const int e = nt*16 + l15;
        float sig = EPSC * (SigmaS[g*4096 + d*64 + e] - 131072.f*cml[d]*cml[e]);
        if (d == e) sig += (1.f/131072.f);
        const float sn = sig * rT;
        const unsigned short hi = f2bf(sn);
        SNh[d*STR + e] = hi;
        SNl[d*STR + e] = f2bf(sn - bf2f(hi));
        const float pv = (d == e) ? 1.f : 0.f;
        Pf[nt][r] = pv;
        Ph[d*STR + e] = f2bf(pv);
        Pl_[d*STR + e] = 0;
      }
    }
    __syncthreads();

    #define MM(AH, AL, BH, BL, OUT)                                            \
    {                                                                          \
      _Pragma("unroll")                                                        \
      for (int nt = 0; nt < 4; ++nt) OUT[nt] = (floatx4){0.f,0.f,0.f,0.f};     \
      _Pragma("unroll")                                                        \
      for (int ks = 0; ks < 2; ++ks){                                          \
        const int ko = ks*32 + q*8;                                            \
        short8 ah = *(const short8*)&AH[(w4*16 + l15)*STR + ko];               \
        short8 al = *(const short8*)&AL[(w4*16 + l15)*STR + ko];               \
        _Pragma("unroll")                                                      \
        for (int nt = 0; nt < 4; ++nt){                                        \
          short8 bh = *(const short8*)&BH[(nt*16 + l15)*STR + ko];             \
          short8 bl = *(const short8*)&BL[(nt*16 + l15)*STR + ko];             \
          OUT[nt] = __builtin_amdgcn_mfma_f32_16x16x32_bf16(ah, bh, OUT[nt], 0,0,0); \
          OUT[nt] = __builtin_amdgcn_mfma_f32_16x16x32_bf16(ah, bl, OUT[nt], 0,0,0); \
          OUT[nt] = __builtin_amdgcn_mfma_f32_16x16x32_bf16(al, bh, OUT[nt], 0,0,0); \
        }                                                                      \
      }                                                                        \
    }

    #define CONV(FR, H, L)                                                     \
    {                                                                          \
      _Pragma("unroll")                                                        \
      for (int nt = 0; nt < 4; ++nt){                                          \
        _Pragma("unroll")                                                      \
        for (int r = 0; r < 4; ++r){                                           \
          const int d = w4*16 + q*4 + r;                                       \
          const int e = nt*16 + l15;                                           \
          const float x = FR[nt][r];                                           \
          const unsigned short hi = f2bf(x);                                   \
          H[d*STR + e] = hi;                                                   \
          L[d*STR + e] = f2bf(x - bf2f(hi));                                   \
        }                                                                      \
      }                                                                        \
    }

    floatx4 Tf[4];
    for (int it = 0; it < 3; ++it){
      MM(Ph, Pl_, Ph, Pl_, Tf);            // T = P*P
      __syncthreads();
      CONV(Tf, Th, Tl);
      __syncthreads();
      MM(Th, Tl, Ph, Pl_, Tf);             // T = P^3
      __syncthreads();
      CONV(Tf, Th, Tl);
      __syncthreads();
      MM(Th, Tl, SNh, SNl, Tf);            // T = P^3 * Sigma_N
      #pragma unroll
      for (int nt = 0; nt < 4; ++nt)
        #pragma unroll
        for (int r = 0; r < 4; ++r)
          Pf[nt][r] = -0.5f*Pf[nt][r] + 1.5f*Tf[nt][r];
      __syncthreads();
      if (it < 2){
        CONV(Pf, Ph, Pl_);
        __syncthreads();
      }
    }

    #pragma unroll
    for (int nt = 0; nt < 4; ++nt)
      #pragma unroll
      for (int r = 0; r < 4; ++r){
        const int d = w4*16 + q*4 + r;
        const int e = nt*16 + l15;
        PwT[g*4096 + e*64 + d] = wsig * Pf[nt][r];   // transposed store
      }
  } else {
    // ---------------- squeeze-excite, one block per n ----------------
    const int n = blockIdx.x - 4;
    const int lane = t & 63, w4 = t >> 6;
    float* xl  = fbuf;         // 256
    float* hb  = fbuf + 256;   // 64
    float* hnb = fbuf + 320;   // 64

    if (t < 64) *(float4*)&xl[t*4] = *(const float4*)&xvar[n*256 + t*4];
    __syncthreads();

    const float4 xv4 = *(const float4*)&xl[lane*4];
    #pragma unroll
    for (int it = 0; it < 16; ++it){
      const int j = w4*16 + it;
      const float4 wv = *(const float4*)&fc1_w[j*256 + lane*4];
      float v = xv4.x*wv.x + xv4.y*wv.y + xv4.z*wv.z + xv4.w*wv.w;
      v += __shfl_down(v, 32); v += __shfl_down(v, 16);
      v += __shfl_down(v, 8);  v += __shfl_down(v, 4);
      v += __shfl_down(v, 2);  v += __shfl_down(v, 1);
      if (lane == 0) hb[j] = v;
    }
    __syncthreads();

    if (t < 64){
      const float hv = hb[t];
      float s = hv, s2 = hv*hv;
      #pragma unroll
      for (int o = 32; o > 0; o >>= 1){
        s  += __shfl_xor(s,  o);
        s2 += __shfl_xor(s2, o);
      }
      const float mu = s * (1.f/64.f);
      const float var = s2 * (1.f/64.f) - mu*mu;   // biased
      float v = (hv - mu) * rsqrtf(var + LNEPS) * ln_g[t] + ln_b[t];
      hnb[t] = v > 0.f ? v : 0.f;
    }
    __syncthreads();

    const float scale = sqrtf(vsum[0] * (1.f/8192.f));
    const float ascl = (1.f - wsig) / scale;
    const int l15 = lane & 15, rgrp = lane >> 4;
    const float4 hn4 = *(const float4*)&hnb[l15*4];
    #pragma unroll
    for (int it = 0; it < 16; ++it){
      const int c = w4*64 + it*4 + rgrp;
      const float4 wv = *(const float4*)&fc2_w[c*64 + l15*4];
      float v = hn4.x*wv.x + hn4.y*wv.y + hn4.z*wv.z + hn4.w*wv.w;
      v += __shfl_down(v, 8); v += __shfl_down(v, 4);
      v += __shfl_down(v, 2); v += __shfl_down(v, 1);
      if (l15 == 0)
        aOut[n*256 + c] = ascl / (1.f + __expf(-v));
    }
  }
}

// ---------------------------------------------------------------------------
// K4: out[n,g*64+d,hw] = sum_e Pw[d][e]*X[n,g*64+e,hw] + a[n,c]*X[n,c,hw]
// grid (hwtile=32, g=4, n=32), 256 threads, 128-hw tiles.
// Wave w owns d-rows 16w..16w+15 -> P loads are wave-uniform (s_load),
// LDS holds only the fp32 X tile. FMA-bound under the HBM roofline.
// ---------------------------------------------------------------------------
__global__ __launch_bounds__(256, 4) void k_final(
    const float* __restrict__ X, const float* __restrict__ PwT,
    const float* __restrict__ aIn, float* __restrict__ out)
{
  const int bx = blockIdx.x, g = blockIdx.y, n = blockIdx.z;
  const int t = threadIdx.x;
  __shared__ float xt[64*128];   // 32 KiB, row stride 128 (contiguous = conflict-free)

  const float* Xg = X + (size_t)(n*256 + g*64)*4096 + bx*128;
  {
    float4 v[8];
    #pragma unroll
    for (int c = 0; c < 8; ++c){
      const int id = c*256 + t;          // 16B chunk id, [0,2048)
      const int e = id >> 5;             // 32 chunks per 128-float row
      const int hw4 = (id & 31) << 2;
      v[c] = *(const float4*)(Xg + (size_t)e*4096 + hw4);
    }
    #pragma unroll
    for (int c = 0; c < 8; ++c){
      const int id = c*256 + t;
      *(float4*)&xt[id << 2] = v[c];
    }
  }
  __syncthreads();

  const int wv = __builtin_amdgcn_readfirstlane(t >> 6);  // force wave-uniform
  const int lane = t & 63;
  const float* Pr = PwT + g*4096 + wv*16;    // Pr[e*64 + dd], uniform address
  const float* ar = aIn + n*256 + g*64 + wv*16;

  float2 acc[16];
  #pragma unroll
  for (int dd = 0; dd < 16; ++dd){
    const int d = wv*16 + dd;
    const float2 xv = *(const float2*)&xt[d*128 + lane*2];
    const float av = ar[dd];               // uniform scalar
    acc[dd].x = av * xv.x; acc[dd].y = av * xv.y;
  }

  #pragma unroll 2
  for (int e = 0; e < 64; ++e){
    const float2 xv = *(const float2*)&xt[e*128 + lane*2];
    const float* pe = Pr + e*64;
    #pragma unroll
    for (int d4 = 0; d4 < 4; ++d4){
      const float4 p = *(const float4*)(pe + d4*4);   // uniform -> s_load
      acc[d4*4+0].x += p.x*xv.x; acc[d4*4+0].y += p.x*xv.y;
      acc[d4*4+1].x += p.y*xv.x; acc[d4*4+1].y += p.y*xv.y;
      acc[d4*4+2].x += p.z*xv.x; acc[d4*4+2].y += p.z*xv.y;
      acc[d4*4+3].x += p.w*xv.x; acc[d4*4+3].y += p.w*xv.y;
    }
  }

  float* ob = out + (size_t)(n*256 + g*64 + wv*16)*4096 + bx*128 + lane*2;
  #pragma unroll
  for (int dd = 0; dd < 16; ++dd)
    *(float2*)(ob + (size_t)dd*4096) = acc[dd];
}

// ---------------------------------------------------------------------------
extern "C" void kernel_launch(void* const* d_in, const int* in_sizes, int n_in,
                              void* d_out, int out_size, void* d_ws, size_t ws_size,
                              hipStream_t stream)
{
  const float* X     = (const float*)d_in[0];
  const float* fc1_w = (const float*)d_in[1];
  const float* ln_g  = (const float*)d_in[2];
  const float* ln_b  = (const float*)d_in[3];
  const float* fc2_w = (const float*)d_in[4];
  const float* xw    = (const float*)d_in[5];
  float* out = (float*)d_out;

  char* ws = (char*)d_ws;
  float* gramP  = (float*)ws;                  // 512*4096*4 = 8 MiB
  float* S1p    = (float*)(ws + 8388608);      // 128 KiB
  float* S2p    = (float*)(ws + 8519680);      // 128 KiB
  float* SigmaS = (float*)(ws + 8650752);      // 64 KiB
  float* PwTb   = (float*)(ws + 8716288);      // 64 KiB
  float* aB     = (float*)(ws + 8781824);      // 32 KiB
  float* xvarB  = (float*)(ws + 8814592);      // 32 KiB
  float* cmeanB = (float*)(ws + 8847360);      // 1 KiB
  float* vsumB  = (float*)(ws + 8848384);      // 4 B

  k_stats_gram<<<dim3(4, 4, 32), 256, 0, stream>>>(X, S1p, S2p, gramP);
  k_reduce<<<65, 256, 0, stream>>>(gramP, S1p, S2p, SigmaS, xvarB, cmeanB, vsumB);
  k_mid2<<<36, 256, 0, stream>>>(SigmaS, cmeanB, xvarB, vsumB,
                                 fc1_w, ln_g, ln_b, fc2_w, xw, PwTb, aB);
  k_final<<<dim3(32, 4, 32), 256, 0, stream>>>(X, PwTb, aB, out);
}